// Round 1
// baseline (466.262 us; speedup 1.0000x reference)
//
#include <hip/hip_runtime.h>

// DataEmbedding_inverted_LSTM on MI355X (gfx950).
// Pipeline: K0a ve_W->bf16 B-frags, K0b S[d]=row-sums, K1 x_proj (f32->bf16),
// K2 LSTM scan (1 wave / batch elem, DPP quad gates, readlane h->SGPR),
// K3 batched MFMA G = h^T @ ve_W^T (bf16) + fused fc epilogue (f32).

typedef unsigned short u16;
typedef unsigned int u32;
typedef float v4f __attribute__((ext_vector_type(4)));
typedef __bf16 v8bf __attribute__((ext_vector_type(8)));

#define LOG2E 1.44269504088896340736f

#define BATCH 1024
#define TSEQ 512
#define CIN 46
#define NH 16
#define NCH 46
#define DM 512

static constexpr size_t XP_BYTES  = (size_t)BATCH * TSEQ * 64 * 2;   // 64 MiB bf16 gate preacts
static constexpr size_t HSF_BYTES = (size_t)BATCH * 16 * 512 * 2;    // 16 MiB bf16 h A-frags
static constexpr size_t VEF_BYTES = (size_t)32 * 16 * 512 * 2;       // 512 KiB bf16 ve B-frags

static __device__ __forceinline__ u16 f2bf(float f) {
  u32 u = __float_as_uint(f);
  u32 r = (u + 0x7FFFu + ((u >> 16) & 1u)) >> 16;  // RNE
  return (u16)r;
}
static __device__ __forceinline__ float bf2f(u16 h) {
  return __uint_as_float(((u32)h) << 16);
}

template <int K>
static __device__ __forceinline__ float qb(float x) {  // broadcast quad-lane K
  return __int_as_float(__builtin_amdgcn_mov_dpp(__float_as_int(x), K * 0x55, 0xF, 0xF, true));
}

// ---------------- K0a: ve_W (f32 [512][512]) -> bf16 B-fragments ----------------
// frag tile (D0,T0): lane l holds B[k=8*(l>>4)+e][n=l&15] = ve_W[D0*16+(l&15)][T0*32+8*(l>>4)+e]
__global__ void k_vefrag(const float* __restrict__ veW, u16* __restrict__ vef) {
  int D0 = blockIdx.x >> 4, T0 = blockIdx.x & 15;
  int lane = threadIdx.x;
  int d = D0 * 16 + (lane & 15);
  int t = T0 * 32 + (lane >> 4) * 8;
  const float* src = veW + (size_t)d * 512 + t;
  float4 v0 = *(const float4*)(src);
  float4 v1 = *(const float4*)(src + 4);
  uint4 o;
  o.x = (u32)f2bf(v0.x) | ((u32)f2bf(v0.y) << 16);
  o.y = (u32)f2bf(v0.z) | ((u32)f2bf(v0.w) << 16);
  o.z = (u32)f2bf(v1.x) | ((u32)f2bf(v1.y) << 16);
  o.w = (u32)f2bf(v1.z) | ((u32)f2bf(v1.w) << 16);
  *(uint4*)(vef + ((size_t)(D0 * 16 + T0)) * 512 + lane * 8) = o;
}

// ---------------- K0b: S[d] = sum_t ve_W[d][t] ----------------
__global__ void k_vesum(const float* __restrict__ veW, float* __restrict__ S) {
  int d = blockIdx.x * 64 + threadIdx.x;
  const float4* r = (const float4*)(veW + (size_t)d * 512);
  float a0 = 0.f, a1 = 0.f, a2 = 0.f, a3 = 0.f;
#pragma unroll 8
  for (int i = 0; i < 128; ++i) {
    float4 v = r[i];
    a0 += v.x; a1 += v.y; a2 += v.z; a3 += v.w;
  }
  S[d] = (a0 + a1) + (a2 + a3);
}

// ---------------- K1: x_proj[b,t,lane] = x[b,t,:] . W_ih[row(lane),:] + bias ----------------
// lane layout (quad-interleaved for K2): gate type q=lane&3 (i,f,g,o), channel j=lane>>2,
// torch row = q*16 + j. x row loaded via wave-uniform (scalar) loads.
__global__ __launch_bounds__(256) void k_xproj(
    const float* __restrict__ x, const float* __restrict__ Wih,
    const float* __restrict__ bih, const float* __restrict__ bhh,
    u16* __restrict__ xp) {
  int lane = threadIdx.x & 63;
  int warp = __builtin_amdgcn_readfirstlane((int)(threadIdx.x >> 6));
  int wid = blockIdx.x * 4 + warp;               // 0..4095
  int rowt = (lane & 3) * 16 + (lane >> 2);
  float w[CIN];
#pragma unroll
  for (int c = 0; c < CIN; ++c) w[c] = Wih[rowt * CIN + c];
  float bias = bih[rowt] + bhh[rowt];
  size_t r0 = (size_t)wid * 128;
#pragma unroll 2
  for (int i = 0; i < 128; ++i) {
    const float* xr = x + (r0 + i) * CIN;        // wave-uniform -> s_load
    float a0 = bias, a1 = 0.f, a2 = 0.f, a3 = 0.f;
#pragma unroll
    for (int c = 0; c < 44; c += 4) {
      a0 = fmaf(xr[c + 0], w[c + 0], a0);
      a1 = fmaf(xr[c + 1], w[c + 1], a1);
      a2 = fmaf(xr[c + 2], w[c + 2], a2);
      a3 = fmaf(xr[c + 3], w[c + 3], a3);
    }
    a0 = fmaf(xr[44], w[44], a0);
    a1 = fmaf(xr[45], w[45], a1);
    xp[(r0 + i) * 64 + lane] = f2bf((a0 + a1) + (a2 + a3));
  }
}

// ---------------- K2: LSTM scan. 1 wave = 1 batch element ----------------
__global__ __launch_bounds__(256) void k_lstm(
    const u16* __restrict__ xp, const float* __restrict__ Whh,
    u16* __restrict__ hsf) {
  int lane = threadIdx.x & 63;
  int warp = __builtin_amdgcn_readfirstlane((int)(threadIdx.x >> 6));
  int b = blockIdx.x * 4 + warp;
  int q = lane & 3, j = lane >> 2;
  int rowt = q * 16 + j;
  float w[NH];
#pragma unroll
  for (int k = 0; k < NH; ++k) w[k] = Whh[rowt * NH + k];
  // sigmoid for q in {0,1,3}: s = 1/(1+exp2(-v*log2e)); tanh for q==2: 2*sig(2v)-1
  float kmul = (q == 2) ? (-2.f * LOG2E) : (-LOG2E);
  float ka = (q == 2) ? 2.f : 1.f;
  float kb = (q == 2) ? -1.f : 0.f;
  float c = 0.f;
  float hreg[NH];
#pragma unroll
  for (int k = 0; k < NH; ++k) hreg[k] = 0.f;

  __shared__ __align__(16) u16 stage[4][512];    // per-warp 1 KiB A-frag staging
  u16* st = stage[warp];

  const u16* gxp = xp + (size_t)b * TSEQ * 64 + lane;
  u16* hb = hsf + (size_t)b * 16 * 512;

  u16 bufA[32], bufB[32];
#pragma unroll
  for (int i = 0; i < 32; ++i) bufA[i] = gxp[(size_t)i * 64];

  auto STEP = [&](float gx, int i) {
    float a0 = fmaf(hreg[0], w[0], gx);
    float a1 = hreg[1] * w[1];
    float a2 = hreg[2] * w[2];
    float a3 = hreg[3] * w[3];
#pragma unroll
    for (int k = 4; k < 16; k += 4) {
      a0 = fmaf(hreg[k + 0], w[k + 0], a0);
      a1 = fmaf(hreg[k + 1], w[k + 1], a1);
      a2 = fmaf(hreg[k + 2], w[k + 2], a2);
      a3 = fmaf(hreg[k + 3], w[k + 3], a3);
    }
    float v = (a0 + a1) + (a2 + a3);
    float e = __builtin_amdgcn_exp2f(v * kmul);
    float s = __builtin_amdgcn_rcpf(1.f + e);
    float act = fmaf(s, ka, kb);
    float iv = qb<0>(act), fv = qb<1>(act), gv = qb<2>(act), ov = qb<3>(act);
    c = fmaf(fv, c, iv * gv);
    float e2 = __builtin_amdgcn_exp2f(c * (-2.f * LOG2E));
    float s2 = __builtin_amdgcn_rcpf(1.f + e2);
    float th = fmaf(s2, 2.f, -1.f);
    float hv = ov * th;
    // stage h (bf16) in MFMA A-frag layout: elem (j, t&31) -> lane j+16*((t&31)>>3), idx t&7
    if (q == (i >> 3)) st[(j + 16 * (i >> 3)) * 8 + (i & 7)] = f2bf(hv);
    // h_j uniform across wave -> SGPRs for next step
#pragma unroll
    for (int k = 0; k < 16; ++k)
      hreg[k] = __int_as_float(__builtin_amdgcn_readlane(__float_as_int(hv), 4 * k));
  };

  for (int p = 0; p < 16; p += 2) {
#pragma unroll
    for (int i = 0; i < 32; ++i) bufB[i] = gxp[((size_t)(p + 1) * 32 + i) * 64];
#pragma unroll
    for (int i = 0; i < 32; ++i) STEP(bf2f(bufA[i]), i);
    uint4 dv = *(uint4*)(st + lane * 8);
    *(uint4*)(hb + (size_t)p * 512 + lane * 8) = dv;
    if (p + 2 < 16) {
#pragma unroll
      for (int i = 0; i < 32; ++i) bufA[i] = gxp[((size_t)(p + 2) * 32 + i) * 64];
    }
#pragma unroll
    for (int i = 0; i < 32; ++i) STEP(bf2f(bufB[i]), i);
    uint4 dv2 = *(uint4*)(st + lane * 8);
    *(uint4*)(hb + (size_t)(p + 1) * 512 + lane * 8) = dv2;
  }
}

// ---------------- K3: G[b] = h[b]^T @ ve_W^T (bf16 MFMA), fused fc epilogue ----------------
// block = 4 batch elems, wave w owns d-range [w*128, w*128+128).
__global__ __launch_bounds__(256, 1) void k_gemm(
    const u16* __restrict__ hsf, const u16* __restrict__ vef,
    const float* __restrict__ fcW, const float* __restrict__ fcb,
    const float* __restrict__ S, const float* __restrict__ veb,
    float* __restrict__ out) {
  int lane = threadIdx.x & 63;
  int warp = __builtin_amdgcn_readfirstlane((int)(threadIdx.x >> 6));
  int bbase = blockIdx.x * 4;
  __shared__ __align__(16) float Glds[4][2][16][128];  // 64 KiB, wave-private regions

  v4f acc[4][8];
#pragma unroll
  for (int bi = 0; bi < 4; ++bi)
#pragma unroll
    for (int dt = 0; dt < 8; ++dt) acc[bi][dt] = (v4f){0.f, 0.f, 0.f, 0.f};

  const u16* ap0 = hsf + (size_t)bbase * 16 * 512 + lane * 8;
  const u16* bp0 = vef + (size_t)warp * 8 * 16 * 512 + lane * 8;

#pragma unroll 2
  for (int kk = 0; kk < 16; ++kk) {
    v8bf a[4], bf[8];
#pragma unroll
    for (int bi = 0; bi < 4; ++bi) {
      uint4 t = *(const uint4*)(ap0 + ((size_t)bi * 16 + kk) * 512);
      a[bi] = __builtin_bit_cast(v8bf, t);
    }
#pragma unroll
    for (int dt = 0; dt < 8; ++dt) {
      uint4 t = *(const uint4*)(bp0 + ((size_t)dt * 16 + kk) * 512);
      bf[dt] = __builtin_bit_cast(v8bf, t);
    }
#pragma unroll
    for (int bi = 0; bi < 4; ++bi)
#pragma unroll
      for (int dt = 0; dt < 8; ++dt)
        acc[bi][dt] = __builtin_amdgcn_mfma_f32_16x16x32_bf16(a[bi], bf[dt], acc[bi][dt], 0, 0, 0);
  }

  // epilogue: out[b,ch,d] = sum_j fcW[ch,j]*G[j,d] + fcb[ch]*S[d] + veb[d]
  int m4 = (lane >> 4) * 4;   // D row = m4+r (j), col = lane&15 (d within 16-tile)
  int nn = lane & 15;
  int dq = lane & 31;
  int bsel = lane >> 5;
  v4f S4 = *(const v4f*)(S + warp * 128 + dq * 4);
  v4f veb4 = *(const v4f*)(veb + warp * 128 + dq * 4);

#pragma unroll
  for (int hh = 0; hh < 2; ++hh) {
#pragma unroll
    for (int bi2 = 0; bi2 < 2; ++bi2)
#pragma unroll
      for (int dt = 0; dt < 8; ++dt)
#pragma unroll
        for (int r = 0; r < 4; ++r)
          Glds[warp][bi2][m4 + r][dt * 16 + nn] = acc[2 * hh + bi2][dt][r];
    v4f g4[16];
#pragma unroll
    for (int jj = 0; jj < 16; ++jj)
      g4[jj] = *(const v4f*)&Glds[warp][bsel][jj][dq * 4];
    size_t b = (size_t)bbase + 2 * hh + bsel;
    float* ob = out + b * (size_t)(NCH * DM) + warp * 128 + dq * 4;
#pragma unroll 2
    for (int ch = 0; ch < NCH; ++ch) {
      float fb = fcb[ch];
      v4f o4 = S4 * fb + veb4;
#pragma unroll
      for (int jj = 0; jj < 16; ++jj) o4 += fcW[ch * 16 + jj] * g4[jj];
      *(v4f*)(ob + (size_t)ch * DM) = o4;
    }
  }
}

extern "C" void kernel_launch(void* const* d_in, const int* in_sizes, int n_in,
                              void* d_out, int out_size, void* d_ws, size_t ws_size,
                              hipStream_t stream) {
  (void)in_sizes; (void)n_in; (void)out_size; (void)ws_size;
  const float* x   = (const float*)d_in[0];
  const float* Wih = (const float*)d_in[2];
  const float* Whh = (const float*)d_in[3];
  const float* bih = (const float*)d_in[4];
  const float* bhh = (const float*)d_in[5];
  const float* fcW = (const float*)d_in[6];
  const float* fcb = (const float*)d_in[7];
  const float* veW = (const float*)d_in[8];
  const float* veb = (const float*)d_in[9];
  float* out = (float*)d_out;

  char* ws = (char*)d_ws;
  u16* xp   = (u16*)ws;
  u16* hsf  = (u16*)(ws + XP_BYTES);
  u16* vef  = (u16*)(ws + XP_BYTES + HSF_BYTES);
  float* S  = (float*)(ws + XP_BYTES + HSF_BYTES + VEF_BYTES);

  hipLaunchKernelGGL(k_vefrag, dim3(512), dim3(64), 0, stream, veW, vef);
  hipLaunchKernelGGL(k_vesum, dim3(8), dim3(64), 0, stream, veW, S);
  hipLaunchKernelGGL(k_xproj, dim3(1024), dim3(256), 0, stream, x, Wih, bih, bhh, xp);
  hipLaunchKernelGGL(k_lstm, dim3(256), dim3(256), 0, stream, xp, Whh, hsf);
  hipLaunchKernelGGL(k_gemm, dim3(256), dim3(256), 0, stream, hsf, vef, fcW, fcb, S, veb, out);
}

// Round 2
// 328.056 us; speedup vs baseline: 1.4213x; 1.4213x over previous
//
#include <hip/hip_runtime.h>

// DataEmbedding_inverted_LSTM on MI355X (gfx950).
// Pipeline: K0a ve_W->bf16 B-frags, K0b S[d]=row-sums, K1 x_proj via MFMA
// (f32->bf16, output in D-native tile layout), K2 LSTM scan (1 wave / batch
// elem, DPP quad gates, readlane h->SGPR), K3 batched MFMA G = h^T @ ve_W^T
// (bf16) + fused fc epilogue (f32).

typedef unsigned short u16;
typedef unsigned int u32;
typedef float v4f __attribute__((ext_vector_type(4)));
typedef __bf16 v8bf __attribute__((ext_vector_type(8)));

#define LOG2E 1.44269504088896340736f

#define BATCH 1024
#define TSEQ 512
#define CIN 46
#define NH 16
#define NCH 46
#define DM 512

static constexpr size_t XP_BYTES  = (size_t)BATCH * TSEQ * 64 * 2;   // 64 MiB bf16 gate preacts
static constexpr size_t HSF_BYTES = (size_t)BATCH * 16 * 512 * 2;    // 16 MiB bf16 h A-frags
static constexpr size_t VEF_BYTES = (size_t)32 * 16 * 512 * 2;       // 512 KiB bf16 ve B-frags

static __device__ __forceinline__ u16 f2bf(float f) {
  u32 u = __float_as_uint(f);
  u32 r = (u + 0x7FFFu + ((u >> 16) & 1u)) >> 16;  // RNE
  return (u16)r;
}
static __device__ __forceinline__ float bf2f(u16 h) {
  return __uint_as_float(((u32)h) << 16);
}
static __device__ __forceinline__ u32 cvt_pk_bf16(float lo, float hi) {
  u32 r;
  asm("v_cvt_pk_bf16_f32 %0, %1, %2" : "=v"(r) : "v"(lo), "v"(hi));
  return r;
}

template <int K>
static __device__ __forceinline__ float qb(float x) {  // broadcast quad-lane K
  return __int_as_float(__builtin_amdgcn_mov_dpp(__float_as_int(x), K * 0x55, 0xF, 0xF, true));
}

// ---------------- K0a: ve_W (f32 [512][512]) -> bf16 B-fragments ----------------
// frag tile (D0,T0): lane l holds B[k=8*(l>>4)+e][n=l&15] = ve_W[D0*16+(l&15)][T0*32+8*(l>>4)+e]
__global__ void k_vefrag(const float* __restrict__ veW, u16* __restrict__ vef) {
  int D0 = blockIdx.x >> 4, T0 = blockIdx.x & 15;
  int lane = threadIdx.x;
  int d = D0 * 16 + (lane & 15);
  int t = T0 * 32 + (lane >> 4) * 8;
  const float* src = veW + (size_t)d * 512 + t;
  float4 v0 = *(const float4*)(src);
  float4 v1 = *(const float4*)(src + 4);
  uint4 o;
  o.x = cvt_pk_bf16(v0.x, v0.y);
  o.y = cvt_pk_bf16(v0.z, v0.w);
  o.z = cvt_pk_bf16(v1.x, v1.y);
  o.w = cvt_pk_bf16(v1.z, v1.w);
  *(uint4*)(vef + ((size_t)(D0 * 16 + T0)) * 512 + lane * 8) = o;
}

// ---------------- K0b: S[d] = sum_t ve_W[d][t], 16 lanes per row ----------------
__global__ void k_vesum(const float* __restrict__ veW, float* __restrict__ S) {
  int t = blockIdx.x * 256 + threadIdx.x;   // 8192 threads
  int d = t >> 4, seg = t & 15;
  const float4* r = (const float4*)(veW + (size_t)d * 512 + seg * 32);
  float a0 = 0.f, a1 = 0.f, a2 = 0.f, a3 = 0.f;
#pragma unroll
  for (int i = 0; i < 8; ++i) {
    float4 v = r[i];
    a0 += v.x; a1 += v.y; a2 += v.z; a3 += v.w;
  }
  float s = (a0 + a1) + (a2 + a3);
#pragma unroll
  for (int o = 1; o < 16; o <<= 1) s += __shfl_xor(s, o, 64);
  if (seg == 0) S[d] = s;
}

// ---------------- K1: x_proj via MFMA ----------------
// preact[row, g] = x[row,:].Wih[g,:] + bias[g];  g split as q=g/16 (gate), j=g%16.
// Per wave: 32 rows (2 M-tiles), N-tiles = q (B cols = j), K = 46 padded to 64.
// Output layout (bf16): xp[rowblk][q][lane][r] with rowblk=row/16,
// lane=(trow>>2)*16+j, r=trow&3  (D-native, coalesced dwordx2 stores).
__global__ __launch_bounds__(256) void k_xprojm(
    const float* __restrict__ x, const float* __restrict__ Wih,
    const float* __restrict__ bih, const float* __restrict__ bhh,
    u16* __restrict__ xp) {
  int lane = threadIdx.x & 63;
  int warp = threadIdx.x >> 6;
  int l15 = lane & 15, lg = lane >> 4;
  long wid = (long)blockIdx.x * 4 + warp;   // 0..16383, 32 rows each
  long rowbase = wid * 32;

  // B-frags bf[q][ks]: lane holds B[k=ks*32+8*lg+e][j=l15] = Wih[q*16+j][k]
  v8bf bfr[4][2];
#pragma unroll
  for (int q = 0; q < 4; ++q) {
    int g = q * 16 + l15;
#pragma unroll
    for (int ks = 0; ks < 2; ++ks) {
      int koff = ks * 32 + lg * 8;
      float bv[8];
#pragma unroll
      for (int e = 0; e < 8; ++e) {
        int c = koff + e;
        int cc = c < 45 ? c : 45;
        float v = Wih[g * 46 + cc];
        bv[e] = (c < 46) ? v : 0.f;
      }
      uint4 wp;
      wp.x = cvt_pk_bf16(bv[0], bv[1]);
      wp.y = cvt_pk_bf16(bv[2], bv[3]);
      wp.z = cvt_pk_bf16(bv[4], bv[5]);
      wp.w = cvt_pk_bf16(bv[6], bv[7]);
      bfr[q][ks] = __builtin_bit_cast(v8bf, wp);
    }
  }

  // bias (init accumulators): depends on (q, j=l15) only
  v4f acc[2][4];
#pragma unroll
  for (int q = 0; q < 4; ++q) {
    float bb = bih[q * 16 + l15] + bhh[q * 16 + l15];
#pragma unroll
    for (int mt = 0; mt < 2; ++mt) acc[mt][q] = (v4f){bb, bb, bb, bb};
  }

#pragma unroll
  for (int mt = 0; mt < 2; ++mt) {
    long row = rowbase + mt * 16 + l15;
    const float* xb = x + row * 46;
#pragma unroll
    for (int ks = 0; ks < 2; ++ks) {
      int koff = ks * 32 + lg * 8;
      float av[8];
#pragma unroll
      for (int i = 0; i < 4; ++i) {
        int c0 = koff + 2 * i;
        int cc = c0 < 44 ? c0 : 44;     // clamp (pairs stay in-bounds)
        float2 v2 = *(const float2*)(xb + cc);
        av[2 * i] = v2.x;
        av[2 * i + 1] = v2.y;
      }
      if (ks == 1) {                     // zero-mask padded K columns
#pragma unroll
        for (int e = 0; e < 8; ++e)
          if (koff + e >= 46) av[e] = 0.f;
      }
      uint4 ap;
      ap.x = cvt_pk_bf16(av[0], av[1]);
      ap.y = cvt_pk_bf16(av[2], av[3]);
      ap.z = cvt_pk_bf16(av[4], av[5]);
      ap.w = cvt_pk_bf16(av[6], av[7]);
      v8bf a = __builtin_bit_cast(v8bf, ap);
#pragma unroll
      for (int q = 0; q < 4; ++q)
        acc[mt][q] = __builtin_amdgcn_mfma_f32_16x16x32_bf16(a, bfr[q][ks], acc[mt][q], 0, 0, 0);
    }
  }

  // store: tile (mt,q) -> xp[(rowblk*4+q)*256 + lane*4 + r]
#pragma unroll
  for (int mt = 0; mt < 2; ++mt) {
    long rowblk = wid * 2 + mt;
#pragma unroll
    for (int q = 0; q < 4; ++q) {
      uint2 o;
      o.x = cvt_pk_bf16(acc[mt][q][0], acc[mt][q][1]);
      o.y = cvt_pk_bf16(acc[mt][q][2], acc[mt][q][3]);
      *(uint2*)(xp + ((rowblk * 4 + q) * 256 + lane * 4)) = o;
    }
  }
}

// ---------------- K2: LSTM scan. 1 wave = 1 batch element ----------------
__global__ __launch_bounds__(256) void k_lstm(
    const u16* __restrict__ xp, const float* __restrict__ Whh,
    u16* __restrict__ hsf) {
  int lane = threadIdx.x & 63;
  int warp = __builtin_amdgcn_readfirstlane((int)(threadIdx.x >> 6));
  int b = blockIdx.x * 4 + warp;
  int q = lane & 3, j = lane >> 2;
  int rowt = q * 16 + j;
  float w[NH];
#pragma unroll
  for (int k = 0; k < NH; ++k) w[k] = Whh[rowt * NH + k];
  // sigmoid for q in {0,1,3}: s = 1/(1+exp2(-v*log2e)); tanh for q==2: 2*sig(2v)-1
  float kmul = (q == 2) ? (-2.f * LOG2E) : (-LOG2E);
  float ka = (q == 2) ? 2.f : 1.f;
  float kb = (q == 2) ? -1.f : 0.f;
  float c = 0.f;
  float hreg[NH];
#pragma unroll
  for (int k = 0; k < NH; ++k) hreg[k] = 0.f;

  __shared__ __align__(16) u16 stage[4][512];    // per-warp 1 KiB A-frag staging
  u16* st = stage[warp];

  // xp gather base for this lane's (q,j): chunk p covers steps 32p..32p+31,
  // c2 in 0..7 -> mt = 2p + (c2>>2), t4 = c2&3; dwordx2 holds r=0..3.
  const u16* xq = xp + (size_t)b * 32768;
  u16* hb = hsf + (size_t)b * 16 * 512;

  uint2 bufA[8], bufB[8];
  auto LOADC = [&](uint2* buf, int p) {
#pragma unroll
    for (int c2 = 0; c2 < 8; ++c2) {
      int mt = 2 * p + (c2 >> 2), t4 = c2 & 3;
      buf[c2] = *(const uint2*)(xq + ((size_t)(mt * 4 + q) * 256 + (t4 * 16 + j) * 4));
    }
  };
  LOADC(bufA, 0);

  auto GX = [&](uint2* buf, int i) -> float {
    int c2 = ((i >> 4) << 2) | ((i >> 2) & 3);
    u32 word = (i & 2) ? buf[c2].y : buf[c2].x;
    u16 hx = (i & 1) ? (u16)(word >> 16) : (u16)(word & 0xFFFFu);
    return bf2f(hx);
  };

  auto STEP = [&](float gx, int i) {
    float a0 = fmaf(hreg[0], w[0], gx);
    float a1 = hreg[1] * w[1];
    float a2 = hreg[2] * w[2];
    float a3 = hreg[3] * w[3];
#pragma unroll
    for (int k = 4; k < 16; k += 4) {
      a0 = fmaf(hreg[k + 0], w[k + 0], a0);
      a1 = fmaf(hreg[k + 1], w[k + 1], a1);
      a2 = fmaf(hreg[k + 2], w[k + 2], a2);
      a3 = fmaf(hreg[k + 3], w[k + 3], a3);
    }
    float v = (a0 + a1) + (a2 + a3);
    float e = __builtin_amdgcn_exp2f(v * kmul);
    float s = __builtin_amdgcn_rcpf(1.f + e);
    float act = fmaf(s, ka, kb);
    float iv = qb<0>(act), fv = qb<1>(act), gv = qb<2>(act), ov = qb<3>(act);
    c = fmaf(fv, c, iv * gv);
    float e2 = __builtin_amdgcn_exp2f(c * (-2.f * LOG2E));
    float s2 = __builtin_amdgcn_rcpf(1.f + e2);
    float th = fmaf(s2, 2.f, -1.f);
    float hv = ov * th;
    // stage h (bf16) in MFMA A-frag layout: elem (j, t&31) -> lane j+16*((t&31)>>3), idx t&7
    if (q == (i >> 3)) st[(j + 16 * (i >> 3)) * 8 + (i & 7)] = f2bf(hv);
    // h_j uniform across wave -> SGPRs for next step
#pragma unroll
    for (int k = 0; k < 16; ++k)
      hreg[k] = __int_as_float(__builtin_amdgcn_readlane(__float_as_int(hv), 4 * k));
  };

  for (int p = 0; p < 16; p += 2) {
    LOADC(bufB, p + 1);
#pragma unroll
    for (int i = 0; i < 32; ++i) STEP(GX(bufA, i), i);
    uint4 dv = *(uint4*)(st + lane * 8);
    *(uint4*)(hb + (size_t)p * 512 + lane * 8) = dv;
    if (p + 2 < 16) LOADC(bufA, p + 2);
#pragma unroll
    for (int i = 0; i < 32; ++i) STEP(GX(bufB, i), i);
    uint4 dv2 = *(uint4*)(st + lane * 8);
    *(uint4*)(hb + (size_t)(p + 1) * 512 + lane * 8) = dv2;
  }
}

// ---------------- K3: G[b] = h[b]^T @ ve_W^T (bf16 MFMA), fused fc epilogue ----------------
// block = 4 batch elems, wave w owns d-range [w*128, w*128+128).
__global__ __launch_bounds__(256, 1) void k_gemm(
    const u16* __restrict__ hsf, const u16* __restrict__ vef,
    const float* __restrict__ fcW, const float* __restrict__ fcb,
    const float* __restrict__ S, const float* __restrict__ veb,
    float* __restrict__ out) {
  int lane = threadIdx.x & 63;
  int warp = __builtin_amdgcn_readfirstlane((int)(threadIdx.x >> 6));
  int bbase = blockIdx.x * 4;
  __shared__ __align__(16) float Glds[4][2][16][128];  // 64 KiB, wave-private regions

  v4f acc[4][8];
#pragma unroll
  for (int bi = 0; bi < 4; ++bi)
#pragma unroll
    for (int dt = 0; dt < 8; ++dt) acc[bi][dt] = (v4f){0.f, 0.f, 0.f, 0.f};

  const u16* ap0 = hsf + (size_t)bbase * 16 * 512 + lane * 8;
  const u16* bp0 = vef + (size_t)warp * 8 * 16 * 512 + lane * 8;

#pragma unroll 2
  for (int kk = 0; kk < 16; ++kk) {
    v8bf a[4], bf[8];
#pragma unroll
    for (int bi = 0; bi < 4; ++bi) {
      uint4 t = *(const uint4*)(ap0 + ((size_t)bi * 16 + kk) * 512);
      a[bi] = __builtin_bit_cast(v8bf, t);
    }
#pragma unroll
    for (int dt = 0; dt < 8; ++dt) {
      uint4 t = *(const uint4*)(bp0 + ((size_t)dt * 16 + kk) * 512);
      bf[dt] = __builtin_bit_cast(v8bf, t);
    }
#pragma unroll
    for (int bi = 0; bi < 4; ++bi)
#pragma unroll
      for (int dt = 0; dt < 8; ++dt)
        acc[bi][dt] = __builtin_amdgcn_mfma_f32_16x16x32_bf16(a[bi], bf[dt], acc[bi][dt], 0, 0, 0);
  }

  // epilogue: out[b,ch,d] = sum_j fcW[ch,j]*G[j,d] + fcb[ch]*S[d] + veb[d]
  int m4 = (lane >> 4) * 4;   // D row = m4+r (j), col = lane&15 (d within 16-tile)
  int nn = lane & 15;
  int dq = lane & 31;
  int bsel = lane >> 5;
  v4f S4 = *(const v4f*)(S + warp * 128 + dq * 4);
  v4f veb4 = *(const v4f*)(veb + warp * 128 + dq * 4);

#pragma unroll
  for (int hh = 0; hh < 2; ++hh) {
#pragma unroll
    for (int bi2 = 0; bi2 < 2; ++bi2)
#pragma unroll
      for (int dt = 0; dt < 8; ++dt)
#pragma unroll
        for (int r = 0; r < 4; ++r)
          Glds[warp][bi2][m4 + r][dt * 16 + nn] = acc[2 * hh + bi2][dt][r];
    v4f g4[16];
#pragma unroll
    for (int jj = 0; jj < 16; ++jj)
      g4[jj] = *(const v4f*)&Glds[warp][bsel][jj][dq * 4];
    size_t b = (size_t)bbase + 2 * hh + bsel;
    float* ob = out + b * (size_t)(NCH * DM) + warp * 128 + dq * 4;
#pragma unroll 2
    for (int ch = 0; ch < NCH; ++ch) {
      float fb = fcb[ch];
      v4f o4 = S4 * fb + veb4;
#pragma unroll
      for (int jj = 0; jj < 16; ++jj) o4 += fcW[ch * 16 + jj] * g4[jj];
      *(v4f*)(ob + (size_t)ch * DM) = o4;
    }
  }
}

extern "C" void kernel_launch(void* const* d_in, const int* in_sizes, int n_in,
                              void* d_out, int out_size, void* d_ws, size_t ws_size,
                              hipStream_t stream) {
  (void)in_sizes; (void)n_in; (void)out_size; (void)ws_size;
  const float* x   = (const float*)d_in[0];
  const float* Wih = (const float*)d_in[2];
  const float* Whh = (const float*)d_in[3];
  const float* bih = (const float*)d_in[4];
  const float* bhh = (const float*)d_in[5];
  const float* fcW = (const float*)d_in[6];
  const float* fcb = (const float*)d_in[7];
  const float* veW = (const float*)d_in[8];
  const float* veb = (const float*)d_in[9];
  float* out = (float*)d_out;

  char* ws = (char*)d_ws;
  u16* xp   = (u16*)ws;
  u16* hsf  = (u16*)(ws + XP_BYTES);
  u16* vef  = (u16*)(ws + XP_BYTES + HSF_BYTES);
  float* S  = (float*)(ws + XP_BYTES + HSF_BYTES + VEF_BYTES);

  hipLaunchKernelGGL(k_vefrag, dim3(512), dim3(64), 0, stream, veW, vef);
  hipLaunchKernelGGL(k_vesum, dim3(32), dim3(256), 0, stream, veW, S);
  hipLaunchKernelGGL(k_xprojm, dim3(4096), dim3(256), 0, stream, x, Wih, bih, bhh, xp);
  hipLaunchKernelGGL(k_lstm, dim3(256), dim3(256), 0, stream, xp, Whh, hsf);
  hipLaunchKernelGGL(k_gemm, dim3(256), dim3(256), 0, stream, hsf, vef, fcW, fcb, S, veb, out);
}